// Round 1
// baseline (19523.405 us; speedup 1.0000x reference)
//
#include <hip/hip_runtime.h>
#include <math.h>

// ---------------------------------------------------------------------------
// HardVectorQuantizer on MI355X — fp32 baseline (round 1)
//  K1 norms:   zz[t]=||z_t||^2, ee[k]=||e_k||^2
//  K2 argmin:  fused 64x64-tile vector GEMM + running argmin (8 code splits)
//  K3 reduce:  merge 8 split partials -> final index per token
//  K4 gather:  z_q, z_residual, sse (double atomic), counts histogram
//  K5 stats:   n_valid, entropy/perplexity, codes_used, vq_loss scalars
// ---------------------------------------------------------------------------

#define DDIM 512
#define MTOK 8192
#define KCODE 8192
#define NOUTE (MTOK * DDIM)   // 4194304

#define NSPLIT 8
#define BT 64                 // tokens per block
#define BC 64                 // codes per tile
#define DKC 32                // D-chunk
#define NCHUNK (DDIM / DKC)   // 16
#define CPS (KCODE / NSPLIT)  // 1024 codes per split
#define TILES (CPS / BC)      // 16

// ws layout (bytes)
#define OFF_EE      0u
#define OFF_ZZ      (OFF_EE + KCODE * 4u)                  // 32768
#define OFF_PDIST   (OFF_ZZ + MTOK * 4u)                   // 65536
#define OFF_PIDX    (OFF_PDIST + NSPLIT * MTOK * 4u)       // 327680
#define OFF_FIDX    (OFF_PIDX + NSPLIT * MTOK * 4u)        // 589824
#define OFF_COUNTS  (OFF_FIDX + MTOK * 4u)                 // 622592
#define OFF_SSE     (OFF_COUNTS + KCODE * 4u)              // 655360 (8B aligned)

// ---------------------------------------------------------------- K1: norms
__global__ __launch_bounds__(256) void norms_kernel(const float* __restrict__ z,
                                                    const float* __restrict__ emb,
                                                    float* __restrict__ zz,
                                                    float* __restrict__ ee) {
  const int row = blockIdx.x * 4 + (threadIdx.x >> 6);
  const int lane = threadIdx.x & 63;
  const float* src;
  float* dst;
  int r;
  if (row < KCODE) { src = emb + (size_t)row * DDIM; dst = ee; r = row; }
  else             { src = z + (size_t)(row - KCODE) * DDIM; dst = zz; r = row - KCODE; }
  const float4* s4 = reinterpret_cast<const float4*>(src);
  const float4 a = s4[lane * 2 + 0];
  const float4 b = s4[lane * 2 + 1];
  float s = a.x * a.x + a.y * a.y + a.z * a.z + a.w * a.w
          + b.x * b.x + b.y * b.y + b.z * b.z + b.w * b.w;
#pragma unroll
  for (int off = 32; off > 0; off >>= 1) s += __shfl_down(s, off, 64);
  if (lane == 0) dst[r] = s;
}

// scatter one float4 into transposed LDS tile (row stride 64)
__device__ __forceinline__ void stash(float* dst, int baseIdx, float4 v) {
  dst[baseIdx + 0 * BT] = v.x;
  dst[baseIdx + 1 * BT] = v.y;
  dst[baseIdx + 2 * BT] = v.z;
  dst[baseIdx + 3 * BT] = v.w;
}

// --------------------------------------------------------------- K2: argmin
__global__ __launch_bounds__(256, 4) void argmin_kernel(const float* __restrict__ z,
                                                        const float* __restrict__ emb,
                                                        const float* __restrict__ zz,
                                                        const float* __restrict__ ee,
                                                        float* __restrict__ pdist,
                                                        int* __restrict__ pidx) {
  // transposed, XOR-swizzled tiles: element (d, tok) lives at
  //   [d * 64 + (((tok>>2) ^ (d>>2)) & 15) * 4 + (tok & 3)]
  // -> b128 fragment reads stay 16B-aligned; staging writes are 2-way max.
  __shared__ float zs[2][DKC * BT];
  __shared__ float es[2][DKC * BC];

  const int tid = threadIdx.x;
  const int tx = tid & 15;   // code quad
  const int ty = tid >> 4;   // token quad
  const int tokBase = blockIdx.x * BT;
  const int split = blockIdx.y;
  const int codeBase0 = split * CPS;

  // staging granules: g = it*256 + tid, d4 = g&7 (float4 within 32-d chunk),
  // tokL = g>>3 (row within 64-row tile). 8 lanes per 128B row-segment.
  const int d4_0 = tid & 7, tokL0 = tid >> 3;
  const int d4_1 = (256 + tid) & 7, tokL1 = (256 + tid) >> 3;
  const int zl0 = (d4_0 * 4) * BT + ((((tokL0 >> 2) ^ d4_0) & 15) * 4) + (tokL0 & 3);
  const int zl1 = (d4_1 * 4) * BT + ((((tokL1 >> 2) ^ d4_1) & 15) * 4) + (tokL1 & 3);
  const float* zg0 = z + (size_t)(tokBase + tokL0) * DDIM + d4_0 * 4;
  const float* zg1 = z + (size_t)(tokBase + tokL1) * DDIM + d4_1 * 4;

  float zzr[4];
#pragma unroll
  for (int i = 0; i < 4; ++i) zzr[i] = zz[tokBase + ty * 4 + i];

  float bestd[4];
  int besti[4];
#pragma unroll
  for (int i = 0; i < 4; ++i) { bestd[i] = INFINITY; besti[i] = 0x7fffffff; }

  float4 zr0, zr1, er0, er1;

#pragma unroll 1
  for (int tile = 0; tile < TILES; ++tile) {
    const int codeBase = codeBase0 + tile * BC;
    const float* eg0 = emb + (size_t)(codeBase + tokL0) * DDIM + d4_0 * 4;
    const float* eg1 = emb + (size_t)(codeBase + tokL1) * DDIM + d4_1 * 4;

    float eer[4];
#pragma unroll
    for (int j = 0; j < 4; ++j) eer[j] = ee[codeBase + tx * 4 + j];

    float acc[4][4];
#pragma unroll
    for (int i = 0; i < 4; ++i)
#pragma unroll
      for (int j = 0; j < 4; ++j) acc[i][j] = 0.f;

    // stage chunk 0 -> buf 0
    zr0 = *reinterpret_cast<const float4*>(zg0);
    zr1 = *reinterpret_cast<const float4*>(zg1);
    er0 = *reinterpret_cast<const float4*>(eg0);
    er1 = *reinterpret_cast<const float4*>(eg1);
    stash(&zs[0][0], zl0, zr0);
    stash(&zs[0][0], zl1, zr1);
    stash(&es[0][0], zl0, er0);
    stash(&es[0][0], zl1, er1);

#pragma unroll 1
    for (int c = 0; c < NCHUNK; ++c) {
      __syncthreads();
      if (c + 1 < NCHUNK) {  // issue next-chunk loads early; latency hides under FMAs
        const int off = (c + 1) * DKC;
        zr0 = *reinterpret_cast<const float4*>(zg0 + off);
        zr1 = *reinterpret_cast<const float4*>(zg1 + off);
        er0 = *reinterpret_cast<const float4*>(eg0 + off);
        er1 = *reinterpret_cast<const float4*>(eg1 + off);
      }
      const int buf = c & 1;
#pragma unroll
      for (int kk = 0; kk < DKC; ++kk) {
        const int sgz = ((ty ^ (kk >> 2)) & 15) * 4;
        const float4 a = *reinterpret_cast<const float4*>(&zs[buf][kk * BT + sgz]);
        const int sge = ((tx ^ (kk >> 2)) & 15) * 4;
        const float4 b = *reinterpret_cast<const float4*>(&es[buf][kk * BC + sge]);
        const float av[4] = {a.x, a.y, a.z, a.w};
        const float bv[4] = {b.x, b.y, b.z, b.w};
#pragma unroll
        for (int i = 0; i < 4; ++i)
#pragma unroll
          for (int j = 0; j < 4; ++j) acc[i][j] = fmaf(av[i], bv[j], acc[i][j]);
      }
      if (c + 1 < NCHUNK) {
        __syncthreads();
        const int nb = (c + 1) & 1;
        stash(&zs[nb][0], zl0, zr0);
        stash(&zs[nb][0], zl1, zr1);
        stash(&es[nb][0], zl0, er0);
        stash(&es[nb][0], zl1, er1);
      }
    }

    // dist exactly as reference: (zz - 2*dot) + ee; ascending idx => '<' keeps first min
#pragma unroll
    for (int i = 0; i < 4; ++i)
#pragma unroll
      for (int j = 0; j < 4; ++j) {
        const float dist = (zzr[i] - 2.0f * acc[i][j]) + eer[j];
        const int idx = codeBase + tx * 4 + j;
        if (dist < bestd[i]) { bestd[i] = dist; besti[i] = idx; }
      }
  }

  // cross-thread (tx) reduction per token
  __syncthreads();
  float* redd = &zs[0][0];                       // 64 x 16 floats
  int* redi = reinterpret_cast<int*>(&es[0][0]); // 64 x 16 ints
#pragma unroll
  for (int i = 0; i < 4; ++i) {
    redd[(ty * 4 + i) * 16 + tx] = bestd[i];
    redi[(ty * 4 + i) * 16 + tx] = besti[i];
  }
  __syncthreads();
  if (tid < 64) {
    float bd = INFINITY;
    int bi = 0x7fffffff;
#pragma unroll
    for (int x = 0; x < 16; ++x) {
      const float dx = redd[tid * 16 + x];
      const int ix = redi[tid * 16 + x];
      if (dx < bd || (dx == bd && ix < bi)) { bd = dx; bi = ix; }
    }
    pdist[split * MTOK + tokBase + tid] = bd;
    pidx[split * MTOK + tokBase + tid] = bi;
  }
}

// ------------------------------------------------------ K3: merge the splits
__global__ __launch_bounds__(256) void reduce_splits(const float* __restrict__ pdist,
                                                     const int* __restrict__ pidx,
                                                     int* __restrict__ fidx) {
  const int t = blockIdx.x * 256 + threadIdx.x;
  float bd = INFINITY;
  int bi = 0x7fffffff;
#pragma unroll
  for (int s = 0; s < NSPLIT; ++s) {
    const float d = pdist[s * MTOK + t];
    const int ix = pidx[s * MTOK + t];
    if (d < bd || (d == bd && ix < bi)) { bd = d; bi = ix; }
  }
  fidx[t] = bi;
}

// ------------------------------------- K4: gather + residual + sse + counts
__global__ __launch_bounds__(256) void gather_kernel(const float* __restrict__ z,
                                                     const float* __restrict__ emb,
                                                     const int* __restrict__ fidx,
                                                     const unsigned char* __restrict__ mask,
                                                     float* __restrict__ out,
                                                     float* __restrict__ counts,
                                                     double* __restrict__ sse) {
  const int t = blockIdx.x * 4 + (threadIdx.x >> 6);  // one wave per token
  const int lane = threadIdx.x & 63;
  const int idx = fidx[t];
  const float* zp = z + (size_t)t * DDIM;
  const float* ep = emb + (size_t)idx * DDIM;
  float* rp = out + (size_t)t * DDIM;                       // z_residual
  float* qp = out + (size_t)NOUTE + 1 + (size_t)t * DDIM;   // z_q (odd offset -> scalar stores)
  float s = 0.f;
#pragma unroll
  for (int j = 0; j < 8; ++j) {
    const int d = j * 64 + lane;  // coalesced 256B per instruction
    const float zv = zp[d];
    const float ev = ep[d];
    const float r = zv - ev;
    rp[d] = r;
    qp[d] = ev;
    s = fmaf(r, r, s);
  }
#pragma unroll
  for (int off = 32; off > 0; off >>= 1) s += __shfl_down(s, off, 64);
  if (lane == 0) {
    const float w = mask[t] ? 0.0f : 1.0f;  // valid-position weight
    atomicAdd(sse, (double)s * (double)w);
    atomicAdd(&counts[idx], w);
  }
}

// ------------------------------------------------------------- K5: scalars
__global__ __launch_bounds__(1024) void stats_kernel(const float* __restrict__ counts,
                                                     const unsigned char* __restrict__ mask,
                                                     const double* __restrict__ sse,
                                                     float* __restrict__ out) {
  __shared__ double sd[1024];
  __shared__ int si[1024];
  const int tid = threadIdx.x;

  int nv = 0;
  for (int i = tid; i < MTOK; i += 1024) nv += (mask[i] ? 0 : 1);
  si[tid] = nv;
  __syncthreads();
#pragma unroll
  for (int s = 512; s > 0; s >>= 1) {
    if (tid < s) si[tid] += si[tid + s];
    __syncthreads();
  }
  const int n_valid = si[0];
  __syncthreads();

  double ct = 0.0;
  for (int k = tid; k < KCODE; k += 1024) ct += (double)counts[k];
  sd[tid] = ct;
  __syncthreads();
#pragma unroll
  for (int s = 512; s > 0; s >>= 1) {
    if (tid < s) sd[tid] += sd[tid + s];
    __syncthreads();
  }
  const float total = fmaxf((float)sd[0], 1.0f);
  __syncthreads();

  double ent = 0.0;
  int used = 0;
  for (int k = tid; k < KCODE; k += 1024) {
    const float c = counts[k];
    if (c > 0.f) ++used;
    const float p = c / total;
    ent += (double)(p * logf(p + 1e-10f));  // fp32 per-element math, mirrors jnp
  }
  sd[tid] = ent;
  si[tid] = used;
  __syncthreads();
#pragma unroll
  for (int s = 512; s > 0; s >>= 1) {
    if (tid < s) { sd[tid] += sd[tid + s]; si[tid] += si[tid + s]; }
    __syncthreads();
  }
  if (tid == 0) {
    const float entropy = -(float)sd[0];
    const float perp = expf(entropy);
    const int usedc = si[0];
    const int nv1 = n_valid > 1 ? n_valid : 1;
    const float denom = (float)(nv1 * DDIM);
    const float L = (float)sse[0] / denom;   // loss_codebook == loss_commit numerically
    out[NOUTE] = L + 0.25f * L;              // vq_loss
    out[2 * NOUTE + 1] = perp;               // perplexity
    out[2 * NOUTE + 2] = (float)usedc;       // codes_used
    out[2 * NOUTE + 3] = (float)usedc / (float)KCODE;
  }
}

// ---------------------------------------------------------------------------
extern "C" void kernel_launch(void* const* d_in, const int* in_sizes, int n_in,
                              void* d_out, int out_size, void* d_ws, size_t ws_size,
                              hipStream_t stream) {
  const float* z = (const float*)d_in[0];
  // padding_mask is a bool array (1 byte each). All-False in this benchmark;
  // byte-reading is also correct if the harness widened it to int32 zeros.
  const unsigned char* mask = (const unsigned char*)d_in[1];
  const float* emb = (const float*)d_in[2];
  float* out = (float*)d_out;
  char* ws = (char*)d_ws;

  float* ee = (float*)(ws + OFF_EE);
  float* zz = (float*)(ws + OFF_ZZ);
  float* pdist = (float*)(ws + OFF_PDIST);
  int* pidx = (int*)(ws + OFF_PIDX);
  int* fidx = (int*)(ws + OFF_FIDX);
  float* counts = (float*)(ws + OFF_COUNTS);
  double* sse = (double*)(ws + OFF_SSE);

  // counts + sse must start at zero (ws is poisoned 0xAA before every launch)
  hipMemsetAsync(ws + OFF_COUNTS, 0, KCODE * 4 + 8, stream);

  hipLaunchKernelGGL(norms_kernel, dim3((KCODE + MTOK) / 4), dim3(256), 0, stream,
                     z, emb, zz, ee);
  hipLaunchKernelGGL(argmin_kernel, dim3(MTOK / BT, NSPLIT), dim3(256), 0, stream,
                     z, emb, zz, ee, pdist, pidx);
  hipLaunchKernelGGL(reduce_splits, dim3(MTOK / 256), dim3(256), 0, stream,
                     pdist, pidx, fidx);
  hipLaunchKernelGGL(gather_kernel, dim3(MTOK / 4), dim3(256), 0, stream,
                     z, emb, fidx, mask, out, counts, sse);
  hipLaunchKernelGGL(stats_kernel, dim3(1), dim3(1024), 0, stream,
                     counts, mask, sse, out);
}

// Round 3
// 1854.860 us; speedup vs baseline: 10.5255x; 10.5255x over previous
//
#include <hip/hip_runtime.h>
#include <math.h>

// ---------------------------------------------------------------------------
// HardVectorQuantizer on MI355X — fp32, round 3
// R1: passed, 19.5 ms; argmin spilled (VGPR clamped to 64 by launch_bounds
//     (256,4)) -> 70 GB scratch traffic.
// R2: (256,2) + 1D XCD-affine grid -> core dump on a reused container; cause
//     ambiguous (indices re-audited clean). Reverting to R1 structure.
// R3: exact R1 code with ONE change: argmin __launch_bounds__(256) (no
//     min-waves clamp) so the accumulators stay in registers.
//  K1 norms:   zz[t]=||z_t||^2, ee[k]=||e_k||^2
//  K2 argmin:  fused 64x64-tile vector GEMM + running argmin (8 code splits)
//  K3 reduce:  merge 8 split partials -> final index per token
//  K4 gather:  z_q, z_residual, sse (double atomic), counts histogram
//  K5 stats:   n_valid, entropy/perplexity, codes_used, vq_loss scalars
// ---------------------------------------------------------------------------

#define DDIM 512
#define MTOK 8192
#define KCODE 8192
#define NOUTE (MTOK * DDIM)   // 4194304

#define NSPLIT 8
#define BT 64                 // tokens per block
#define BC 64                 // codes per tile
#define DKC 32                // D-chunk
#define NCHUNK (DDIM / DKC)   // 16
#define CPS (KCODE / NSPLIT)  // 1024 codes per split
#define TILES (CPS / BC)      // 16

// ws layout (bytes)
#define OFF_EE      0u
#define OFF_ZZ      (OFF_EE + KCODE * 4u)                  // 32768
#define OFF_PDIST   (OFF_ZZ + MTOK * 4u)                   // 65536
#define OFF_PIDX    (OFF_PDIST + NSPLIT * MTOK * 4u)       // 327680
#define OFF_FIDX    (OFF_PIDX + NSPLIT * MTOK * 4u)        // 589824
#define OFF_COUNTS  (OFF_FIDX + MTOK * 4u)                 // 622592
#define OFF_SSE     (OFF_COUNTS + KCODE * 4u)              // 655360 (8B aligned)

// ---------------------------------------------------------------- K1: norms
__global__ __launch_bounds__(256) void norms_kernel(const float* __restrict__ z,
                                                    const float* __restrict__ emb,
                                                    float* __restrict__ zz,
                                                    float* __restrict__ ee) {
  const int row = blockIdx.x * 4 + (threadIdx.x >> 6);
  const int lane = threadIdx.x & 63;
  const float* src;
  float* dst;
  int r;
  if (row < KCODE) { src = emb + (size_t)row * DDIM; dst = ee; r = row; }
  else             { src = z + (size_t)(row - KCODE) * DDIM; dst = zz; r = row - KCODE; }
  const float4* s4 = reinterpret_cast<const float4*>(src);
  const float4 a = s4[lane * 2 + 0];
  const float4 b = s4[lane * 2 + 1];
  float s = a.x * a.x + a.y * a.y + a.z * a.z + a.w * a.w
          + b.x * b.x + b.y * b.y + b.z * b.z + b.w * b.w;
#pragma unroll
  for (int off = 32; off > 0; off >>= 1) s += __shfl_down(s, off, 64);
  if (lane == 0) dst[r] = s;
}

// scatter one float4 into transposed LDS tile (row stride 64)
__device__ __forceinline__ void stash(float* dst, int baseIdx, float4 v) {
  dst[baseIdx + 0 * BT] = v.x;
  dst[baseIdx + 1 * BT] = v.y;
  dst[baseIdx + 2 * BT] = v.z;
  dst[baseIdx + 3 * BT] = v.w;
}

// --------------------------------------------------------------- K2: argmin
__global__ __launch_bounds__(256) void argmin_kernel(const float* __restrict__ z,
                                                     const float* __restrict__ emb,
                                                     const float* __restrict__ zz,
                                                     const float* __restrict__ ee,
                                                     float* __restrict__ pdist,
                                                     int* __restrict__ pidx) {
  // transposed, XOR-swizzled tiles: element (d, tok) lives at
  //   [d * 64 + (((tok>>2) ^ (d>>2)) & 15) * 4 + (tok & 3)]
  // -> b128 fragment reads stay 16B-aligned; staging writes are 2-way max.
  __shared__ float zs[2][DKC * BT];
  __shared__ float es[2][DKC * BC];

  const int tid = threadIdx.x;
  const int tx = tid & 15;   // code quad
  const int ty = tid >> 4;   // token quad
  const int tokBase = blockIdx.x * BT;
  const int split = blockIdx.y;
  const int codeBase0 = split * CPS;

  // staging granules: g = it*256 + tid, d4 = g&7 (float4 within 32-d chunk),
  // tokL = g>>3 (row within 64-row tile). 8 lanes per 128B row-segment.
  const int d4_0 = tid & 7, tokL0 = tid >> 3;
  const int d4_1 = (256 + tid) & 7, tokL1 = (256 + tid) >> 3;
  const int zl0 = (d4_0 * 4) * BT + ((((tokL0 >> 2) ^ d4_0) & 15) * 4) + (tokL0 & 3);
  const int zl1 = (d4_1 * 4) * BT + ((((tokL1 >> 2) ^ d4_1) & 15) * 4) + (tokL1 & 3);
  const float* zg0 = z + (size_t)(tokBase + tokL0) * DDIM + d4_0 * 4;
  const float* zg1 = z + (size_t)(tokBase + tokL1) * DDIM + d4_1 * 4;

  float zzr[4];
#pragma unroll
  for (int i = 0; i < 4; ++i) zzr[i] = zz[tokBase + ty * 4 + i];

  float bestd[4];
  int besti[4];
#pragma unroll
  for (int i = 0; i < 4; ++i) { bestd[i] = INFINITY; besti[i] = 0x7fffffff; }

  float4 zr0, zr1, er0, er1;

#pragma unroll 1
  for (int tile = 0; tile < TILES; ++tile) {
    const int codeBase = codeBase0 + tile * BC;
    const float* eg0 = emb + (size_t)(codeBase + tokL0) * DDIM + d4_0 * 4;
    const float* eg1 = emb + (size_t)(codeBase + tokL1) * DDIM + d4_1 * 4;

    float eer[4];
#pragma unroll
    for (int j = 0; j < 4; ++j) eer[j] = ee[codeBase + tx * 4 + j];

    float acc[4][4];
#pragma unroll
    for (int i = 0; i < 4; ++i)
#pragma unroll
      for (int j = 0; j < 4; ++j) acc[i][j] = 0.f;

    // stage chunk 0 -> buf 0
    zr0 = *reinterpret_cast<const float4*>(zg0);
    zr1 = *reinterpret_cast<const float4*>(zg1);
    er0 = *reinterpret_cast<const float4*>(eg0);
    er1 = *reinterpret_cast<const float4*>(eg1);
    stash(&zs[0][0], zl0, zr0);
    stash(&zs[0][0], zl1, zr1);
    stash(&es[0][0], zl0, er0);
    stash(&es[0][0], zl1, er1);

#pragma unroll 1
    for (int c = 0; c < NCHUNK; ++c) {
      __syncthreads();
      if (c + 1 < NCHUNK) {  // issue next-chunk loads early; latency hides under FMAs
        const int off = (c + 1) * DKC;
        zr0 = *reinterpret_cast<const float4*>(zg0 + off);
        zr1 = *reinterpret_cast<const float4*>(zg1 + off);
        er0 = *reinterpret_cast<const float4*>(eg0 + off);
        er1 = *reinterpret_cast<const float4*>(eg1 + off);
      }
      const int buf = c & 1;
#pragma unroll
      for (int kk = 0; kk < DKC; ++kk) {
        const int sgz = ((ty ^ (kk >> 2)) & 15) * 4;
        const float4 a = *reinterpret_cast<const float4*>(&zs[buf][kk * BT + sgz]);
        const int sge = ((tx ^ (kk >> 2)) & 15) * 4;
        const float4 b = *reinterpret_cast<const float4*>(&es[buf][kk * BC + sge]);
        const float av[4] = {a.x, a.y, a.z, a.w};
        const float bv[4] = {b.x, b.y, b.z, b.w};
#pragma unroll
        for (int i = 0; i < 4; ++i)
#pragma unroll
          for (int j = 0; j < 4; ++j) acc[i][j] = fmaf(av[i], bv[j], acc[i][j]);
      }
      if (c + 1 < NCHUNK) {
        __syncthreads();
        const int nb = (c + 1) & 1;
        stash(&zs[nb][0], zl0, zr0);
        stash(&zs[nb][0], zl1, zr1);
        stash(&es[nb][0], zl0, er0);
        stash(&es[nb][0], zl1, er1);
      }
    }

    // dist exactly as reference: (zz - 2*dot) + ee; ascending idx => '<' keeps first min
#pragma unroll
    for (int i = 0; i < 4; ++i)
#pragma unroll
      for (int j = 0; j < 4; ++j) {
        const float dist = (zzr[i] - 2.0f * acc[i][j]) + eer[j];
        const int idx = codeBase + tx * 4 + j;
        if (dist < bestd[i]) { bestd[i] = dist; besti[i] = idx; }
      }
  }

  // cross-thread (tx) reduction per token
  __syncthreads();
  float* redd = &zs[0][0];                       // 64 x 16 floats
  int* redi = reinterpret_cast<int*>(&es[0][0]); // 64 x 16 ints
#pragma unroll
  for (int i = 0; i < 4; ++i) {
    redd[(ty * 4 + i) * 16 + tx] = bestd[i];
    redi[(ty * 4 + i) * 16 + tx] = besti[i];
  }
  __syncthreads();
  if (tid < 64) {
    float bd = INFINITY;
    int bi = 0x7fffffff;
#pragma unroll
    for (int x = 0; x < 16; ++x) {
      const float dx = redd[tid * 16 + x];
      const int ix = redi[tid * 16 + x];
      if (dx < bd || (dx == bd && ix < bi)) { bd = dx; bi = ix; }
    }
    pdist[split * MTOK + tokBase + tid] = bd;
    pidx[split * MTOK + tokBase + tid] = bi;
  }
}

// ------------------------------------------------------ K3: merge the splits
__global__ __launch_bounds__(256) void reduce_splits(const float* __restrict__ pdist,
                                                     const int* __restrict__ pidx,
                                                     int* __restrict__ fidx) {
  const int t = blockIdx.x * 256 + threadIdx.x;
  float bd = INFINITY;
  int bi = 0x7fffffff;
#pragma unroll
  for (int s = 0; s < NSPLIT; ++s) {
    const float d = pdist[s * MTOK + t];
    const int ix = pidx[s * MTOK + t];
    if (d < bd || (d == bd && ix < bi)) { bd = d; bi = ix; }
  }
  fidx[t] = bi;
}

// ------------------------------------- K4: gather + residual + sse + counts
__global__ __launch_bounds__(256) void gather_kernel(const float* __restrict__ z,
                                                     const float* __restrict__ emb,
                                                     const int* __restrict__ fidx,
                                                     const unsigned char* __restrict__ mask,
                                                     float* __restrict__ out,
                                                     float* __restrict__ counts,
                                                     double* __restrict__ sse) {
  const int t = blockIdx.x * 4 + (threadIdx.x >> 6);  // one wave per token
  const int lane = threadIdx.x & 63;
  const int idx = fidx[t];
  const float* zp = z + (size_t)t * DDIM;
  const float* ep = emb + (size_t)idx * DDIM;
  float* rp = out + (size_t)t * DDIM;                       // z_residual
  float* qp = out + (size_t)NOUTE + 1 + (size_t)t * DDIM;   // z_q (odd offset -> scalar stores)
  float s = 0.f;
#pragma unroll
  for (int j = 0; j < 8; ++j) {
    const int d = j * 64 + lane;  // coalesced 256B per instruction
    const float zv = zp[d];
    const float ev = ep[d];
    const float r = zv - ev;
    rp[d] = r;
    qp[d] = ev;
    s = fmaf(r, r, s);
  }
#pragma unroll
  for (int off = 32; off > 0; off >>= 1) s += __shfl_down(s, off, 64);
  if (lane == 0) {
    const float w = mask[t] ? 0.0f : 1.0f;  // valid-position weight
    atomicAdd(sse, (double)s * (double)w);
    atomicAdd(&counts[idx], w);
  }
}

// ------------------------------------------------------------- K5: scalars
__global__ __launch_bounds__(1024) void stats_kernel(const float* __restrict__ counts,
                                                     const unsigned char* __restrict__ mask,
                                                     const double* __restrict__ sse,
                                                     float* __restrict__ out) {
  __shared__ double sd[1024];
  __shared__ int si[1024];
  const int tid = threadIdx.x;

  int nv = 0;
  for (int i = tid; i < MTOK; i += 1024) nv += (mask[i] ? 0 : 1);
  si[tid] = nv;
  __syncthreads();
#pragma unroll
  for (int s = 512; s > 0; s >>= 1) {
    if (tid < s) si[tid] += si[tid + s];
    __syncthreads();
  }
  const int n_valid = si[0];
  __syncthreads();

  double ct = 0.0;
  for (int k = tid; k < KCODE; k += 1024) ct += (double)counts[k];
  sd[tid] = ct;
  __syncthreads();
#pragma unroll
  for (int s = 512; s > 0; s >>= 1) {
    if (tid < s) sd[tid] += sd[tid + s];
    __syncthreads();
  }
  const float total = fmaxf((float)sd[0], 1.0f);
  __syncthreads();

  double ent = 0.0;
  int used = 0;
  for (int k = tid; k < KCODE; k += 1024) {
    const float c = counts[k];
    if (c > 0.f) ++used;
    const float p = c / total;
    ent += (double)(p * logf(p + 1e-10f));  // fp32 per-element math, mirrors jnp
  }
  sd[tid] = ent;
  si[tid] = used;
  __syncthreads();
#pragma unroll
  for (int s = 512; s > 0; s >>= 1) {
    if (tid < s) { sd[tid] += sd[tid + s]; si[tid] += si[tid + s]; }
    __syncthreads();
  }
  if (tid == 0) {
    const float entropy = -(float)sd[0];
    const float perp = expf(entropy);
    const int usedc = si[0];
    const int nv1 = n_valid > 1 ? n_valid : 1;
    const float denom = (float)(nv1 * DDIM);
    const float L = (float)sse[0] / denom;   // loss_codebook == loss_commit numerically
    out[NOUTE] = L + 0.25f * L;              // vq_loss
    out[2 * NOUTE + 1] = perp;               // perplexity
    out[2 * NOUTE + 2] = (float)usedc;       // codes_used
    out[2 * NOUTE + 3] = (float)usedc / (float)KCODE;
  }
}

// ---------------------------------------------------------------------------
extern "C" void kernel_launch(void* const* d_in, const int* in_sizes, int n_in,
                              void* d_out, int out_size, void* d_ws, size_t ws_size,
                              hipStream_t stream) {
  const float* z = (const float*)d_in[0];
  // padding_mask is a bool array (1 byte each). All-False in this benchmark;
  // byte-reading is also correct if the harness widened it to int32 zeros.
  const unsigned char* mask = (const unsigned char*)d_in[1];
  const float* emb = (const float*)d_in[2];
  float* out = (float*)d_out;
  char* ws = (char*)d_ws;

  float* ee = (float*)(ws + OFF_EE);
  float* zz = (float*)(ws + OFF_ZZ);
  float* pdist = (float*)(ws + OFF_PDIST);
  int* pidx = (int*)(ws + OFF_PIDX);
  int* fidx = (int*)(ws + OFF_FIDX);
  float* counts = (float*)(ws + OFF_COUNTS);
  double* sse = (double*)(ws + OFF_SSE);

  // counts + sse must start at zero (ws is poisoned 0xAA before every launch)
  hipMemsetAsync(ws + OFF_COUNTS, 0, KCODE * 4 + 8, stream);

  hipLaunchKernelGGL(norms_kernel, dim3((KCODE + MTOK) / 4), dim3(256), 0, stream,
                     z, emb, zz, ee);
  hipLaunchKernelGGL(argmin_kernel, dim3(MTOK / BT, NSPLIT), dim3(256), 0, stream,
                     z, emb, zz, ee, pdist, pidx);
  hipLaunchKernelGGL(reduce_splits, dim3(MTOK / 256), dim3(256), 0, stream,
                     pdist, pidx, fidx);
  hipLaunchKernelGGL(gather_kernel, dim3(MTOK / 4), dim3(256), 0, stream,
                     z, emb, fidx, mask, out, counts, sse);
  hipLaunchKernelGGL(stats_kernel, dim3(1), dim3(1024), 0, stream,
                     counts, mask, sse, out);
}

// Round 4
// 555.485 us; speedup vs baseline: 35.1466x; 3.3392x over previous
//
#include <hip/hip_runtime.h>
#include <math.h>

// ---------------------------------------------------------------------------
// HardVectorQuantizer on MI355X — round 4: MFMA f16 hi/lo-split distance GEMM
// R3: fp32 VALU argmin 1836 µs (VALUBusy 54%, FMA-issue floor 24% => fp32 is
//     structurally capped ~600 µs). Move the 68.7 GF GEMM to matrix cores:
//     fp32 ~= hi + lo/2048 (f16), dot via 3 MFMAs (hh + cross terms).
//     Error ~3e-7 << fp32 ulp noise on dist (~3e-5); only argmin indices are
//     consumed downstream (K4 recomputes outputs from exact fp32).
//  K0 split:   eh/el (emb*64 hi/lo), zh/zl (z hi/lo) f16 arrays in ws
//  K1 norms:   zz, ee (fp32, unchanged)
//  K2 argmin:  128x128-tile MFMA GEMM + argmin -> 64 code-split partials
//  K3 reduce:  merge 64 splits
//  K4 gather:  z_q, z_residual, sse, counts (unchanged)
//  K5 stats:   scalars (unchanged)
// NOTE: requires ws_size >= ~38 MB.
// ---------------------------------------------------------------------------

#define DDIM 512
#define MTOK 8192
#define KCODE 8192
#define NOUTE (MTOK * DDIM)

#define BM 128                // codes per block
#define BN 128                // tokens per block
#define BK 32                 // K per stage
#define NK (DDIM / BK)        // 16
#define NCT (KCODE / BM)      // 64 code tiles (= splits)
#define NTT (MTOK / BN)       // 64 token tiles

// ws layout (bytes)
#define OFF_EH 0u
#define OFF_EL (OFF_EH + (unsigned)KCODE * DDIM * 2u)      //  8388608
#define OFF_ZH (OFF_EL + (unsigned)KCODE * DDIM * 2u)      // 16777216
#define OFF_ZL (OFF_ZH + (unsigned)MTOK * DDIM * 2u)       // 25165824
#define OFF_EE (OFF_ZL + (unsigned)MTOK * DDIM * 2u)       // 33554432
#define OFF_ZZ (OFF_EE + KCODE * 4u)
#define OFF_PDIST (OFF_ZZ + MTOK * 4u)
#define OFF_PIDX (OFF_PDIST + (unsigned)NCT * MTOK * 4u)
#define OFF_FIDX (OFF_PIDX + (unsigned)NCT * MTOK * 4u)
#define OFF_COUNTS (OFF_FIDX + MTOK * 4u)
#define OFF_SSE (OFF_COUNTS + KCODE * 4u)

typedef _Float16 half8 __attribute__((ext_vector_type(8)));
typedef float f32x16 __attribute__((ext_vector_type(16)));

// ------------------------------------------------- K0: hi/lo f16 split
// emb scaled by 64 (exact) so e_hi/e_lo stay clear of f16 subnormals;
// reconstruction folds in 1/64. lo captures next 11 bits via *2048 (exact pow2).
__global__ __launch_bounds__(256) void split_kernel(const float* __restrict__ z,
                                                    const float* __restrict__ emb,
                                                    _Float16* __restrict__ eh,
                                                    _Float16* __restrict__ el,
                                                    _Float16* __restrict__ zh,
                                                    _Float16* __restrict__ zl) {
  const int row = blockIdx.x * 4 + (threadIdx.x >> 6);
  const int lane = threadIdx.x & 63;
  const float* src;
  _Float16 *dh, *dl;
  float sc;
  int r;
  if (row < KCODE) { src = emb + (size_t)row * DDIM; dh = eh; dl = el; sc = 64.f; r = row; }
  else             { src = z + (size_t)(row - KCODE) * DDIM; dh = zh; dl = zl; sc = 1.f; r = row - KCODE; }
  const float4* s4 = reinterpret_cast<const float4*>(src);
  const float4 v0 = s4[lane * 2 + 0];
  const float4 v1 = s4[lane * 2 + 1];
  const float vv[8] = {v0.x, v0.y, v0.z, v0.w, v1.x, v1.y, v1.z, v1.w};
  half8 hv, lv;
#pragma unroll
  for (int i = 0; i < 8; ++i) {
    const float vs = vv[i] * sc;               // exact (sc is 1 or 64)
    const _Float16 h = (_Float16)vs;
    hv[i] = h;
    lv[i] = (_Float16)((vs - (float)h) * 2048.0f);
  }
  *reinterpret_cast<half8*>(dh + (size_t)r * DDIM + lane * 8) = hv;
  *reinterpret_cast<half8*>(dl + (size_t)r * DDIM + lane * 8) = lv;
}

// ------------------------------------------------- K1: norms (unchanged)
__global__ __launch_bounds__(256) void norms_kernel(const float* __restrict__ z,
                                                    const float* __restrict__ emb,
                                                    float* __restrict__ zz,
                                                    float* __restrict__ ee) {
  const int row = blockIdx.x * 4 + (threadIdx.x >> 6);
  const int lane = threadIdx.x & 63;
  const float* src;
  float* dst;
  int r;
  if (row < KCODE) { src = emb + (size_t)row * DDIM; dst = ee; r = row; }
  else             { src = z + (size_t)(row - KCODE) * DDIM; dst = zz; r = row - KCODE; }
  const float4* s4 = reinterpret_cast<const float4*>(src);
  const float4 a = s4[lane * 2 + 0];
  const float4 b = s4[lane * 2 + 1];
  float s = a.x * a.x + a.y * a.y + a.z * a.z + a.w * a.w
          + b.x * b.x + b.y * b.y + b.z * b.z + b.w * b.w;
#pragma unroll
  for (int off = 32; off > 0; off >>= 1) s += __shfl_down(s, off, 64);
  if (lane == 0) dst[r] = s;
}

// ------------------------------------------------- K2: MFMA GEMM + argmin
// Tiles in LDS: per buffer {Ah, Al, Bh, Bl}, each [128 rows][32 k] f16 = 8 KB,
// 64 B rows, chunk-XOR swizzle: 16B-chunk c of row r stored at c ^ ((r>>1)&3).
// Same XOR on write and read -> bank-uniform (4 words/bank) b128 accesses.
// MFMA: A = emb rows (M=codes), B = z cols (N=tokens), D[row=code][col=token].
// D layout (HW-verified): col = lane&31, row = (reg&3) + 8*(reg>>2) + 4*(lane>>5).
__global__ __launch_bounds__(256) void argmin_mfma_kernel(
    const _Float16* __restrict__ eh, const _Float16* __restrict__ el,
    const _Float16* __restrict__ zh, const _Float16* __restrict__ zl,
    const float* __restrict__ zz, const float* __restrict__ ee,
    float* __restrict__ pdist, int* __restrict__ pidx) {
  __shared__ __align__(16) unsigned char smem[65536];  // 2 x 32 KB buffers

  const int tid = threadIdx.x;
  const int l = tid & 63;
  const int w = tid >> 6;          // wave 0..3
  const int wr = w >> 1;           // code-half of block
  const int wc = w & 1;            // token-half of block
  const int codeBase = blockIdx.x * BM;
  const int tokBase = blockIdx.y * BN;

  // ---- staging: thread covers chunks (r0, c0) and (r0+64, c0) of each tile
  const int r0 = tid >> 2, c0 = tid & 3;
  const int dst0 = r0 * 64 + ((c0 ^ ((r0 >> 1) & 3)) << 4);  // second chunk: +4096
  const size_t eOff = ((size_t)(codeBase + r0) * DDIM + c0 * 8) * 2;  // bytes
  const size_t zOff = ((size_t)(tokBase + r0) * DDIM + c0 * 8) * 2;
  const unsigned ROWSTEP = 64u * DDIM * 2u;  // 64 rows down = 65536 B
  const uint4* p0 = (const uint4*)((const char*)eh + eOff);
  const uint4* p1 = (const uint4*)((const char*)eh + eOff + ROWSTEP);
  const uint4* p2 = (const uint4*)((const char*)el + eOff);
  const uint4* p3 = (const uint4*)((const char*)el + eOff + ROWSTEP);
  const uint4* p4 = (const uint4*)((const char*)zh + zOff);
  const uint4* p5 = (const uint4*)((const char*)zh + zOff + ROWSTEP);
  const uint4* p6 = (const uint4*)((const char*)zl + zOff);
  const uint4* p7 = (const uint4*)((const char*)zl + zOff + ROWSTEP);

  // ---- fragment read offsets
  const int keyR = (l >> 1) & 3;                  // row-swizzle key, lane-const
  const int rowA = wr * 64 + (l & 31);            // + mt*32
  const int rowB = wc * 64 + (l & 31);            // + nt*32
  const int aH = rowA * 64;                       // tile Ah at 0
  const int aL = 8192 + rowA * 64;                // Al
  const int bH = 16384 + rowB * 64;               // Bh
  const int bL = 24576 + rowB * 64;               // Bl

  f32x16 hh[2][2], xx[2][2];
#pragma unroll
  for (int mt = 0; mt < 2; ++mt)
#pragma unroll
    for (int nt = 0; nt < 2; ++nt)
#pragma unroll
      for (int i = 0; i < 16; ++i) { hh[mt][nt][i] = 0.f; xx[mt][nt][i] = 0.f; }

  uint4 s0, s1, s2, s3, s4, s5, s6, s7;
  // prologue: load + stash chunk 0 into buffer 0
  s0 = p0[0]; s1 = p1[0]; s2 = p2[0]; s3 = p3[0];
  s4 = p4[0]; s5 = p5[0]; s6 = p6[0]; s7 = p7[0];
  p0 += 4; p1 += 4; p2 += 4; p3 += 4; p4 += 4; p5 += 4; p6 += 4; p7 += 4;
  {
    char* b = (char*)smem;
    *(uint4*)(b + dst0) = s0;                 *(uint4*)(b + dst0 + 4096) = s1;
    *(uint4*)(b + 8192 + dst0) = s2;          *(uint4*)(b + 8192 + dst0 + 4096) = s3;
    *(uint4*)(b + 16384 + dst0) = s4;         *(uint4*)(b + 16384 + dst0 + 4096) = s5;
    *(uint4*)(b + 24576 + dst0) = s6;         *(uint4*)(b + 24576 + dst0 + 4096) = s7;
  }

#define LDF(off) (*(const half8*)((const char*)smem + (off)))
#define MFMA(a, b, c) __builtin_amdgcn_mfma_f32_32x32x16_f16((a), (b), (c), 0, 0, 0)

#pragma unroll 1
  for (int c = 0; c < NK; ++c) {
    __syncthreads();  // buf[c&1] staged; prior reads done
    if (c + 1 < NK) {  // issue next-chunk loads; land under the MFMAs
      s0 = p0[0]; s1 = p1[0]; s2 = p2[0]; s3 = p3[0];
      s4 = p4[0]; s5 = p5[0]; s6 = p6[0]; s7 = p7[0];
      p0 += 4; p1 += 4; p2 += 4; p3 += 4; p4 += 4; p5 += 4; p6 += 4; p7 += 4;
    }
    const int bo = (c & 1) * 32768;
#pragma unroll
    for (int ks = 0; ks < 2; ++ks) {
      const int cs = ((ks * 2 + (l >> 5)) ^ keyR) << 4;
      const half8 a0h = LDF(bo + aH + cs);
      const half8 a1h = LDF(bo + aH + 2048 + cs);
      const half8 a0l = LDF(bo + aL + cs);
      const half8 a1l = LDF(bo + aL + 2048 + cs);
      const half8 b0h = LDF(bo + bH + cs);
      const half8 b1h = LDF(bo + bH + 2048 + cs);
      const half8 b0l = LDF(bo + bL + cs);
      const half8 b1l = LDF(bo + bL + 2048 + cs);
      hh[0][0] = MFMA(a0h, b0h, hh[0][0]);
      hh[0][1] = MFMA(a0h, b1h, hh[0][1]);
      hh[1][0] = MFMA(a1h, b0h, hh[1][0]);
      hh[1][1] = MFMA(a1h, b1h, hh[1][1]);
      xx[0][0] = MFMA(a0h, b0l, xx[0][0]);
      xx[0][1] = MFMA(a0h, b1l, xx[0][1]);
      xx[1][0] = MFMA(a1h, b0l, xx[1][0]);
      xx[1][1] = MFMA(a1h, b1l, xx[1][1]);
      xx[0][0] = MFMA(a0l, b0h, xx[0][0]);
      xx[0][1] = MFMA(a0l, b1h, xx[0][1]);
      xx[1][0] = MFMA(a1l, b0h, xx[1][0]);
      xx[1][1] = MFMA(a1l, b1h, xx[1][1]);
    }
    if (c + 1 < NK) {
      __syncthreads();  // all reads of buf[(c+1)&1] from iter c-1 are done
      char* b = (char*)smem + ((c + 1) & 1) * 32768;
      *(uint4*)(b + dst0) = s0;                 *(uint4*)(b + dst0 + 4096) = s1;
      *(uint4*)(b + 8192 + dst0) = s2;          *(uint4*)(b + 8192 + dst0 + 4096) = s3;
      *(uint4*)(b + 16384 + dst0) = s4;         *(uint4*)(b + 16384 + dst0 + 4096) = s5;
      *(uint4*)(b + 24576 + dst0) = s6;         *(uint4*)(b + 24576 + dst0 + 4096) = s7;
    }
  }

  // ---- epilogue: dist = (zz - 2*dot) + ee, dot = hh/64 + xx/131072
  __syncthreads();
  float* eeS = (float*)smem;               // [0, 512): ee slice for this block
  float* pd = (float*)(smem + 512);        // 256 partial dists
  int* pi = (int*)(smem + 1536);           // 256 partial idx
  if (tid < BM) eeS[tid] = ee[codeBase + tid];
  __syncthreads();
#pragma unroll
  for (int nt = 0; nt < 2; ++nt) {
    const int lt = wc * 64 + nt * 32 + (l & 31);
    const float ztt = zz[tokBase + lt];
    float bd = INFINITY;
    int bi = 0x7fffffff;
#pragma unroll
    for (int mt = 0; mt < 2; ++mt)
#pragma unroll
      for (int r = 0; r < 16; ++r) {
        const int rowL = wr * 64 + mt * 32 + (r & 3) + ((r >> 2) << 3) + ((l >> 5) << 2);
        const float dot = hh[mt][nt][r] * (1.0f / 64.0f) + xx[mt][nt][r] * (1.0f / 131072.0f);
        const float dist = (ztt - 2.0f * dot) + eeS[rowL];
        const int code = codeBase + rowL;
        if (dist < bd || (dist == bd && code < bi)) { bd = dist; bi = code; }
      }
    const float od = __shfl_xor(bd, 32, 64);
    const int oi = __shfl_xor(bi, 32, 64);
    if (od < bd || (od == bd && oi < bi)) { bd = od; bi = oi; }
    if (l < 32) { pd[w * 64 + nt * 32 + l] = bd; pi[w * 64 + nt * 32 + l] = bi; }
  }
  __syncthreads();
  if (tid < BN) {
    const int wcc = tid >> 6, rest = tid & 63;
    float da = pd[wcc * 64 + rest];
    int ia = pi[wcc * 64 + rest];
    const float db = pd[(2 + wcc) * 64 + rest];
    const int ib = pi[(2 + wcc) * 64 + rest];
    if (db < da || (db == da && ib < ia)) { da = db; ia = ib; }  // wr0 codes < wr1
    pdist[(size_t)blockIdx.x * MTOK + tokBase + tid] = da;
    pidx[(size_t)blockIdx.x * MTOK + tokBase + tid] = ia;
  }
#undef LDF
#undef MFMA
}

// ------------------------------------------------- K3: merge 64 splits
__global__ __launch_bounds__(256) void reduce_splits(const float* __restrict__ pdist,
                                                     const int* __restrict__ pidx,
                                                     int* __restrict__ fidx) {
  const int t = blockIdx.x * 256 + threadIdx.x;
  float bd = INFINITY;
  int bi = 0x7fffffff;
  for (int s = 0; s < NCT; ++s) {
    const float d = pdist[(size_t)s * MTOK + t];
    const int ix = pidx[(size_t)s * MTOK + t];
    if (d < bd || (d == bd && ix < bi)) { bd = d; bi = ix; }
  }
  fidx[t] = bi;
}

// ------------------------- K4: gather + residual + sse + counts (unchanged)
__global__ __launch_bounds__(256) void gather_kernel(const float* __restrict__ z,
                                                     const float* __restrict__ emb,
                                                     const int* __restrict__ fidx,
                                                     const unsigned char* __restrict__ mask,
                                                     float* __restrict__ out,
                                                     float* __restrict__ counts,
                                                     double* __restrict__ sse) {
  const int t = blockIdx.x * 4 + (threadIdx.x >> 6);
  const int lane = threadIdx.x & 63;
  const int idx = fidx[t];
  const float* zp = z + (size_t)t * DDIM;
  const float* ep = emb + (size_t)idx * DDIM;
  float* rp = out + (size_t)t * DDIM;
  float* qp = out + (size_t)NOUTE + 1 + (size_t)t * DDIM;
  float s = 0.f;
#pragma unroll
  for (int j = 0; j < 8; ++j) {
    const int d = j * 64 + lane;
    const float zv = zp[d];
    const float ev = ep[d];
    const float r = zv - ev;
    rp[d] = r;
    qp[d] = ev;
    s = fmaf(r, r, s);
  }
#pragma unroll
  for (int off = 32; off > 0; off >>= 1) s += __shfl_down(s, off, 64);
  if (lane == 0) {
    const float wgt = mask[t] ? 0.0f : 1.0f;
    atomicAdd(sse, (double)s * (double)wgt);
    atomicAdd(&counts[idx], wgt);
  }
}

// ------------------------------------------------- K5: scalars (unchanged)
__global__ __launch_bounds__(1024) void stats_kernel(const float* __restrict__ counts,
                                                     const unsigned char* __restrict__ mask,
                                                     const double* __restrict__ sse,
                                                     float* __restrict__ out) {
  __shared__ double sd[1024];
  __shared__ int si[1024];
  const int tid = threadIdx.x;

  int nv = 0;
  for (int i = tid; i < MTOK; i += 1024) nv += (mask[i] ? 0 : 1);
  si[tid] = nv;
  __syncthreads();
#pragma unroll
  for (int s = 512; s > 0; s >>= 1) {
    if (tid < s) si[tid] += si[tid + s];
    __syncthreads();
  }
  const int n_valid = si[0];
  __syncthreads();

  double ct = 0.0;
  for (int k = tid; k < KCODE; k += 1024) ct += (double)counts[k];
  sd[tid] = ct;
  __syncthreads();
#pragma unroll
  for (int s = 512; s > 0; s >>= 1) {
    if (tid < s) sd[tid] += sd[tid + s];
    __syncthreads();
  }
  const float total = fmaxf((float)sd[0], 1.0f);
  __syncthreads();

  double ent = 0.0;
  int used = 0;
  for (int k = tid; k < KCODE; k += 1024) {
    const float c = counts[k];
    if (c > 0.f) ++used;
    const float p = c / total;
    ent += (double)(p * logf(p + 1e-10f));
  }
  sd[tid] = ent;
  si[tid] = used;
  __syncthreads();
#pragma unroll
  for (int s = 512; s > 0; s >>= 1) {
    if (tid < s) { sd[tid] += sd[tid + s]; si[tid] += si[tid + s]; }
    __syncthreads();
  }
  if (tid == 0) {
    const float entropy = -(float)sd[0];
    const float perp = expf(entropy);
    const int usedc = si[0];
    const int nv1 = n_valid > 1 ? n_valid : 1;
    const float denom = (float)(nv1 * DDIM);
    const float L = (float)sse[0] / denom;
    out[NOUTE] = L + 0.25f * L;
    out[2 * NOUTE + 1] = perp;
    out[2 * NOUTE + 2] = (float)usedc;
    out[2 * NOUTE + 3] = (float)usedc / (float)KCODE;
  }
}

// ---------------------------------------------------------------------------
extern "C" void kernel_launch(void* const* d_in, const int* in_sizes, int n_in,
                              void* d_out, int out_size, void* d_ws, size_t ws_size,
                              hipStream_t stream) {
  const float* z = (const float*)d_in[0];
  const unsigned char* mask = (const unsigned char*)d_in[1];
  const float* emb = (const float*)d_in[2];
  float* out = (float*)d_out;
  char* ws = (char*)d_ws;

  _Float16* eh = (_Float16*)(ws + OFF_EH);
  _Float16* el = (_Float16*)(ws + OFF_EL);
  _Float16* zh = (_Float16*)(ws + OFF_ZH);
  _Float16* zl = (_Float16*)(ws + OFF_ZL);
  float* ee = (float*)(ws + OFF_EE);
  float* zz = (float*)(ws + OFF_ZZ);
  float* pdist = (float*)(ws + OFF_PDIST);
  int* pidx = (int*)(ws + OFF_PIDX);
  int* fidx = (int*)(ws + OFF_FIDX);
  float* counts = (float*)(ws + OFF_COUNTS);
  double* sse = (double*)(ws + OFF_SSE);

  hipMemsetAsync(ws + OFF_COUNTS, 0, KCODE * 4 + 8, stream);

  hipLaunchKernelGGL(split_kernel, dim3((KCODE + MTOK) / 4), dim3(256), 0, stream,
                     z, emb, eh, el, zh, zl);
  hipLaunchKernelGGL(norms_kernel, dim3((KCODE + MTOK) / 4), dim3(256), 0, stream,
                     z, emb, zz, ee);
  hipLaunchKernelGGL(argmin_mfma_kernel, dim3(NCT, NTT), dim3(256), 0, stream,
                     eh, el, zh, zl, zz, ee, pdist, pidx);
  hipLaunchKernelGGL(reduce_splits, dim3(MTOK / 256), dim3(256), 0, stream,
                     pdist, pidx, fidx);
  hipLaunchKernelGGL(gather_kernel, dim3(MTOK / 4), dim3(256), 0, stream,
                     z, emb, fidx, mask, out, counts, sse);
  hipLaunchKernelGGL(stats_kernel, dim3(1), dim3(1024), 0, stream,
                     counts, mask, sse, out);
}

// Round 6
// 436.395 us; speedup vs baseline: 44.7380x; 1.2729x over previous
//
#include <hip/hip_runtime.h>
#include <math.h>

// ---------------------------------------------------------------------------
// HardVectorQuantizer on MI355X — round 6 (= round 5 resubmit; R5 never ran:
// GPU acquisition timeout, no data).
// R4: MFMA hi/lo-split GEMM 379 µs (MfmaUtil 23%), total 555 µs, absmax 0.
//     MFMA floor 83 µs, LDS floor 91 µs -> schedule-bound, not pipe-bound.
// R5/R6: (1) global_load_lds staging (pre-swizzled SOURCE, linear LDS dest,
//         read-side swizzle verbatim from verified R4 — rule 21);
//     (2) 2-phase pipeline: stage-next THEN compute, ONE barrier per K-step;
//     (3) fuse split+norms; cross-block argmin via packed u64 atomicMin
//         (kills pdist/pidx round-trip + reduce kernel).
//  K0 prep:    eh/el/zh/zl f16 hi/lo split + zz/ee norms (one pass)
//  K2 argmin:  128x128 MFMA GEMM -> per-token packed atomicMin
//  K4 gather:  z_q, z_residual, sse, counts
//  K5 stats:   scalars
// ---------------------------------------------------------------------------

#define DDIM 512
#define MTOK 8192
#define KCODE 8192
#define NOUTE (MTOK * DDIM)

#define BM 128
#define BN 128
#define BK 32
#define NK (DDIM / BK)        // 16

// ws layout (bytes)
#define OFF_EH 0u
#define OFF_EL (OFF_EH + (unsigned)KCODE * DDIM * 2u)
#define OFF_ZH (OFF_EL + (unsigned)KCODE * DDIM * 2u)
#define OFF_ZL (OFF_ZH + (unsigned)MTOK * DDIM * 2u)
#define OFF_EE (OFF_ZL + (unsigned)MTOK * DDIM * 2u)       // 32 MB
#define OFF_ZZ (OFF_EE + KCODE * 4u)
#define OFF_PACKED (OFF_ZZ + MTOK * 4u)                    // 8192 x u64
#define OFF_COUNTS (OFF_PACKED + MTOK * 8u)
#define OFF_SSE (OFF_COUNTS + KCODE * 4u)

typedef _Float16 half8 __attribute__((ext_vector_type(8)));
typedef float f32x16 __attribute__((ext_vector_type(16)));

// ------------------------------------------- K0: hi/lo split + norms, fused
__global__ __launch_bounds__(256) void prep_kernel(const float* __restrict__ z,
                                                   const float* __restrict__ emb,
                                                   _Float16* __restrict__ eh,
                                                   _Float16* __restrict__ el,
                                                   _Float16* __restrict__ zh,
                                                   _Float16* __restrict__ zl,
                                                   float* __restrict__ zz,
                                                   float* __restrict__ ee) {
  const int row = blockIdx.x * 4 + (threadIdx.x >> 6);
  const int lane = threadIdx.x & 63;
  const float* src;
  _Float16 *dh, *dl;
  float* nrm;
  float sc;
  int r;
  if (row < KCODE) { src = emb + (size_t)row * DDIM; dh = eh; dl = el; nrm = ee; sc = 64.f; r = row; }
  else { src = z + (size_t)(row - KCODE) * DDIM; dh = zh; dl = zl; nrm = zz; sc = 1.f; r = row - KCODE; }
  const float4* s4 = reinterpret_cast<const float4*>(src);
  const float4 v0 = s4[lane * 2 + 0];
  const float4 v1 = s4[lane * 2 + 1];
  const float vv[8] = {v0.x, v0.y, v0.z, v0.w, v1.x, v1.y, v1.z, v1.w};
  half8 hv, lv;
  float s = 0.f;
#pragma unroll
  for (int i = 0; i < 8; ++i) {
    s = fmaf(vv[i], vv[i], s);
    const float vs = vv[i] * sc;               // exact (sc is 1 or 64)
    const _Float16 h = (_Float16)vs;
    hv[i] = h;
    lv[i] = (_Float16)((vs - (float)h) * 2048.0f);
  }
  *reinterpret_cast<half8*>(dh + (size_t)r * DDIM + lane * 8) = hv;
  *reinterpret_cast<half8*>(dl + (size_t)r * DDIM + lane * 8) = lv;
#pragma unroll
  for (int off = 32; off > 0; off >>= 1) s += __shfl_down(s, off, 64);
  if (lane == 0) nrm[r] = s;
}

// wave-uniform lds base lb, per-lane global src gb: stage one 8 KB tile
// (128 rows x 64 B) as 8 x 1 KB DMA writes. LDS dest is linear (lane*16);
// the XOR swizzle (slot s of row r holds global chunk s ^ ((r>>1)&3)) is
// applied by pre-swizzling the per-lane GLOBAL address (rule 21 / m173).
__device__ __forceinline__ void stage_tile(const char* gb, char* lb) {
#pragma unroll
  for (int i = 0; i < 8; ++i)
    __builtin_amdgcn_global_load_lds(
        (const __attribute__((address_space(1))) unsigned int*)(gb + i * 16384),
        (__attribute__((address_space(3))) unsigned int*)(lb + i * 1024), 16, 0, 0);
}

// ------------------------------------------------- K2: MFMA GEMM + argmin
// LDS per buffer: {Ah, Al, Bh, Bl} each [128 rows][32 k] f16 = 8 KB -> 32 KB;
// double-buffered 64 KB. Wave w DMA-stages tile w. Read side identical to the
// bitwise-verified R4 kernel.
__global__ __launch_bounds__(256) void argmin_mfma_kernel(
    const _Float16* __restrict__ eh, const _Float16* __restrict__ el,
    const _Float16* __restrict__ zh, const _Float16* __restrict__ zl,
    const float* __restrict__ zz, const float* __restrict__ ee,
    unsigned long long* __restrict__ packed) {
  __shared__ __align__(16) unsigned char smem[65536];

  const int tid = threadIdx.x;
  const int l = tid & 63;
  const int w = tid >> 6;          // wave 0..3, stages tile w
  const int wr = w >> 1;           // code-half
  const int wc = w & 1;            // token-half
  const int codeBase = blockIdx.x * BM;
  const int tokBase = blockIdx.y * BN;

  // staging source: instr i, lane l -> LDS row i*16 + (l>>2), slot l&3.
  // slot s of row r must hold global chunk s ^ ((r>>1)&3); with r = i*16+(l>>2)
  // the key reduces to (l>>3)&3 (i*8 == 0 mod 4), so chunk = (l&3)^((l>>3)&3).
  const _Float16* tileSrc = (w == 0) ? eh + (size_t)codeBase * DDIM
                          : (w == 1) ? el + (size_t)codeBase * DDIM
                          : (w == 2) ? zh + (size_t)tokBase * DDIM
                                     : zl + (size_t)tokBase * DDIM;
  const int cS = (l & 3) ^ ((l >> 3) & 3);
  const char* gsrc = (const char*)tileSrc + (size_t)(l >> 2) * 1024 + cS * 16;
  char* ldsTile = (char*)smem + w * 8192;  // wave-uniform

  // fragment read offsets (verbatim R4)
  const int keyR = (l >> 1) & 3;
  const int rowA = wr * 64 + (l & 31);
  const int rowB = wc * 64 + (l & 31);
  const int aH = rowA * 64;
  const int aL = 8192 + rowA * 64;
  const int bH = 16384 + rowB * 64;
  const int bL = 24576 + rowB * 64;

  f32x16 hh[2][2], xx[2][2];
#pragma unroll
  for (int mt = 0; mt < 2; ++mt)
#pragma unroll
    for (int nt = 0; nt < 2; ++nt)
#pragma unroll
      for (int i = 0; i < 16; ++i) { hh[mt][nt][i] = 0.f; xx[mt][nt][i] = 0.f; }

#define LDF(off) (*(const half8*)((const char*)smem + (off)))
#define MFMA(a, b, c) __builtin_amdgcn_mfma_f32_32x32x16_f16((a), (b), (c), 0, 0, 0)

  // prologue: stage K-chunk 0 into buffer 0
  stage_tile(gsrc, ldsTile);
  asm volatile("s_waitcnt vmcnt(0)" ::: "memory");
  __syncthreads();

#pragma unroll 1
  for (int c = 0; c < NK; ++c) {
    const int cur = c & 1;
    if (c + 1 < NK)  // stage next K-chunk into the other buffer (DMA, in flight
      stage_tile(gsrc + (size_t)(c + 1) * 64, ldsTile + (cur ^ 1) * 32768);
    const int bo = cur * 32768;
#pragma unroll
    for (int ks = 0; ks < 2; ++ks) {
      const int cs = ((ks * 2 + (l >> 5)) ^ keyR) << 4;
      const half8 a0h = LDF(bo + aH + cs);
      const half8 a1h = LDF(bo + aH + 2048 + cs);
      const half8 a0l = LDF(bo + aL + cs);
      const half8 a1l = LDF(bo + aL + 2048 + cs);
      const half8 b0h = LDF(bo + bH + cs);
      const half8 b1h = LDF(bo + bH + 2048 + cs);
      const half8 b0l = LDF(bo + bL + cs);
      const half8 b1l = LDF(bo + bL + 2048 + cs);
      hh[0][0] = MFMA(a0h, b0h, hh[0][0]);
      hh[0][1] = MFMA(a0h, b1h, hh[0][1]);
      hh[1][0] = MFMA(a1h, b0h, hh[1][0]);
      hh[1][1] = MFMA(a1h, b1h, hh[1][1]);
      xx[0][0] = MFMA(a0h, b0l, xx[0][0]);
      xx[0][1] = MFMA(a0h, b1l, xx[0][1]);
      xx[1][0] = MFMA(a1h, b0l, xx[1][0]);
      xx[1][1] = MFMA(a1h, b1l, xx[1][1]);
      xx[0][0] = MFMA(a0l, b0h, xx[0][0]);
      xx[0][1] = MFMA(a0l, b1h, xx[0][1]);
      xx[1][0] = MFMA(a1l, b0h, xx[1][0]);
      xx[1][1] = MFMA(a1l, b1h, xx[1][1]);
    }
    // drain this iter's DMA + release buffers: one barrier per K-step
    asm volatile("s_waitcnt vmcnt(0)" ::: "memory");
    __syncthreads();
  }

  // ---- epilogue: dist = (zz - 2*dot) + ee, dot = hh/64 + xx/131072
  float* eeS = (float*)smem;
  float* pd = (float*)(smem + 512);
  int* pi = (int*)(smem + 1536);
  if (tid < BM) eeS[tid] = ee[codeBase + tid];
  __syncthreads();
#pragma unroll
  for (int nt = 0; nt < 2; ++nt) {
    const int lt = wc * 64 + nt * 32 + (l & 31);
    const float ztt = zz[tokBase + lt];
    float bd = INFINITY;
    int bi = 0x7fffffff;
#pragma unroll
    for (int mt = 0; mt < 2; ++mt)
#pragma unroll
      for (int r = 0; r < 16; ++r) {
        const int rowL = wr * 64 + mt * 32 + (r & 3) + ((r >> 2) << 3) + ((l >> 5) << 2);
        const float dot = hh[mt][nt][r] * (1.0f / 64.0f) + xx[mt][nt][r] * (1.0f / 131072.0f);
        const float dist = (ztt - 2.0f * dot) + eeS[rowL];
        const int code = codeBase + rowL;
        if (dist < bd || (dist == bd && code < bi)) { bd = dist; bi = code; }
      }
    const float od = __shfl_xor(bd, 32, 64);
    const int oi = __shfl_xor(bi, 32, 64);
    if (od < bd || (od == bd && oi < bi)) { bd = od; bi = oi; }
    if (l < 32) { pd[w * 64 + nt * 32 + l] = bd; pi[w * 64 + nt * 32 + l] = bi; }
  }
  __syncthreads();
  if (tid < BN) {
    const int wcc = tid >> 6, rest = tid & 63;
    float da = pd[wcc * 64 + rest];
    int ia = pi[wcc * 64 + rest];
    const float db = pd[(2 + wcc) * 64 + rest];
    const int ib = pi[(2 + wcc) * 64 + rest];
    if (db < da || (db == da && ib < ia)) { da = db; ia = ib; }
    // monotone float->u32 map, then lexicographic (dist, idx) min via atomicMin
    unsigned fb = __float_as_uint(da);
    fb ^= ((unsigned)((int)fb >> 31)) | 0x80000000u;
    const unsigned long long key = ((unsigned long long)fb << 32) | (unsigned)ia;
    atomicMin(&packed[tokBase + tid], key);
  }
#undef LDF
#undef MFMA
}

// ------------------------- K4: gather + residual + sse + counts
__global__ __launch_bounds__(256) void gather_kernel(const float* __restrict__ z,
                                                     const float* __restrict__ emb,
                                                     const unsigned long long* __restrict__ packed,
                                                     const unsigned char* __restrict__ mask,
                                                     float* __restrict__ out,
                                                     float* __restrict__ counts,
                                                     double* __restrict__ sse) {
  const int t = blockIdx.x * 4 + (threadIdx.x >> 6);
  const int lane = threadIdx.x & 63;
  const int idx = (int)(packed[t] & 0xffffffffull);
  const float* zp = z + (size_t)t * DDIM;
  const float* ep = emb + (size_t)idx * DDIM;
  float* rp = out + (size_t)t * DDIM;
  float* qp = out + (size_t)NOUTE + 1 + (size_t)t * DDIM;
  float s = 0.f;
#pragma unroll
  for (int j = 0; j < 8; ++j) {
    const int d = j * 64 + lane;
    const float zv = zp[d];
    const float ev = ep[d];
    const float r = zv - ev;
    rp[d] = r;
    qp[d] = ev;
    s = fmaf(r, r, s);
  }
#pragma unroll
  for (int off = 32; off > 0; off >>= 1) s += __shfl_down(s, off, 64);
  if (lane == 0) {
    const float wgt = mask[t] ? 0.0f : 1.0f;
    atomicAdd(sse, (double)s * (double)wgt);
    atomicAdd(&counts[idx], wgt);
  }
}

// ------------------------------------------------- K5: scalars
__global__ __launch_bounds__(1024) void stats_kernel(const float* __restrict__ counts,
                                                     const unsigned char* __restrict__ mask,
                                                     const double* __restrict__ sse,
                                                     float* __restrict__ out) {
  __shared__ double sd[1024];
  __shared__ int si[1024];
  const int tid = threadIdx.x;

  int nv = 0;
  for (int i = tid; i < MTOK; i += 1024) nv += (mask[i] ? 0 : 1);
  si[tid] = nv;
  __syncthreads();
#pragma unroll
  for (int s = 512; s > 0; s >>= 1) {
    if (tid < s) si[tid] += si[tid + s];
    __syncthreads();
  }
  const int n_valid = si[0];
  __syncthreads();

  double ct = 0.0;
  for (int k = tid; k < KCODE; k += 1024) ct += (double)counts[k];
  sd[tid] = ct;
  __syncthreads();
#pragma unroll
  for (int s = 512; s > 0; s >>= 1) {
    if (tid < s) sd[tid] += sd[tid + s];
    __syncthreads();
  }
  const float total = fmaxf((float)sd[0], 1.0f);
  __syncthreads();

  double ent = 0.0;
  int used = 0;
  for (int k = tid; k < KCODE; k += 1024) {
    const float c = counts[k];
    if (c > 0.f) ++used;
    const float p = c / total;
    ent += (double)(p * logf(p + 1e-10f));
  }
  sd[tid] = ent;
  si[tid] = used;
  __syncthreads();
#pragma unroll
  for (int s = 512; s > 0; s >>= 1) {
    if (tid < s) { sd[tid] += sd[tid + s]; si[tid] += si[tid + s]; }
    __syncthreads();
  }
  if (tid == 0) {
    const float entropy = -(float)sd[0];
    const float perp = expf(entropy);
    const int usedc = si[0];
    const int nv1 = n_valid > 1 ? n_valid : 1;
    const float denom = (float)(nv1 * DDIM);
    const float L = (float)sse[0] / denom;
    out[NOUTE] = L + 0.25f * L;
    out[2 * NOUTE + 1] = perp;
    out[2 * NOUTE + 2] = (float)usedc;
    out[2 * NOUTE + 3] = (float)usedc / (float)KCODE;
  }
}

// ---------------------------------------------------------------------------
extern "C" void kernel_launch(void* const* d_in, const int* in_sizes, int n_in,
                              void* d_out, int out_size, void* d_ws, size_t ws_size,
                              hipStream_t stream) {
  const float* z = (const float*)d_in[0];
  const unsigned char* mask = (const unsigned char*)d_in[1];
  const float* emb = (const float*)d_in[2];
  float* out = (float*)d_out;
  char* ws = (char*)d_ws;

  _Float16* eh = (_Float16*)(ws + OFF_EH);
  _Float16* el = (_Float16*)(ws + OFF_EL);
  _Float16* zh = (_Float16*)(ws + OFF_ZH);
  _Float16* zl = (_Float16*)(ws + OFF_ZL);
  float* ee = (float*)(ws + OFF_EE);
  float* zz = (float*)(ws + OFF_ZZ);
  unsigned long long* packed = (unsigned long long*)(ws + OFF_PACKED);
  float* counts = (float*)(ws + OFF_COUNTS);
  double* sse = (double*)(ws + OFF_SSE);

  // packed argmin keys start at u64-max; counts/sse at zero
  hipMemsetAsync(ws + OFF_PACKED, 0xFF, MTOK * 8u, stream);
  hipMemsetAsync(ws + OFF_COUNTS, 0, KCODE * 4u + 8u, stream);

  hipLaunchKernelGGL(prep_kernel, dim3((KCODE + MTOK) / 4), dim3(256), 0, stream,
                     z, emb, eh, el, zh, zl, zz, ee);
  hipLaunchKernelGGL(argmin_mfma_kernel, dim3(KCODE / BM, MTOK / BN), dim3(256), 0, stream,
                     eh, el, zh, zl, zz, ee, packed);
  hipLaunchKernelGGL(gather_kernel, dim3(MTOK / 4), dim3(256), 0, stream,
                     z, emb, packed, mask, out, counts, sse);
  hipLaunchKernelGGL(stats_kernel, dim3(1), dim3(1024), 0, stream,
                     counts, mask, sse, out);
}